// Round 1
// baseline (411.739 us; speedup 1.0000x reference)
//
#include <hip/hip_runtime.h>
#include <math.h>

// ---------------- geometry ----------------
#define SD 64
#define EMO 16
#define DD 80          // D = SD+EMO
#define CC 64          // C
#define EE 320         // E = SD*5
#define NH 4
#define HDM 80         // E/NH
#define FF 400         // F = D*5
#define NS 27
#define NPAIR 351

#define SPLIT_MID 54
#define ROWS_MID 200       // 10800/54
#define SPLIT_ROOT 54
#define ROWS_ROOT 200

// ws layout (floats)
#define WS_QKV   0                 // 27*960 = 25920
#define WS_O     25920             // 27*320 = 8640
#define WS_ENT   34560             // 351*64 = 22464
#define WS_AVG   57024             // 64
#define WS_MIDP  57088             // 27*54*400 = 583200
#define WS_CF    640288            // 10800
#define WS_ROOTP 651088            // 54*400 = 21600
// total 672688 floats = ~2.7 MB

// ---------------- causal (granger) ----------------
__global__ void k_granger(const float* __restrict__ x, const float* __restrict__ h,
                          const float* __restrict__ gW, const float* __restrict__ gb,
                          float* __restrict__ out) {
    int idx = blockIdx.x * 256 + threadIdx.x;
    if (idx >= NS * NS) return;
    int i = idx / NS, j = idx % NS;
    const float* hr = h + j * 320;
    const float* xr = x + i * 320;
    float acc = gb[0];
    for (int k = 0; k < 320; ++k) acc += hr[k] * gW[k] + xr[k] * gW[320 + k];
    float sig = 1.0f / (1.0f + expf(-acc));
    out[idx] = (i == j) ? 0.0f : sig;
}

// ---------------- qkv = x @ W_in^T + b ----------------
__global__ void k_qkv(const float* __restrict__ x, const float* __restrict__ W,
                      const float* __restrict__ b, float* __restrict__ qkv) {
    int idx = blockIdx.x * 256 + threadIdx.x;
    if (idx >= NS * 3 * EE) return;
    int i = idx / (3 * EE), c = idx % (3 * EE);
    const float4* xr = (const float4*)(x + i * 320);
    const float4* wr = (const float4*)(W + (size_t)c * 320);
    float acc = b[c];
    for (int k = 0; k < 80; ++k) {
        float4 a = xr[k], w = wr[k];
        acc += a.x * w.x + a.y * w.y + a.z * w.z + a.w * w.w;
    }
    qkv[idx] = acc;
}

// ---------------- per (head, query) attention ----------------
__global__ void k_attn(const float* __restrict__ qkv, float* __restrict__ o) {
    int h = blockIdx.x / NS, q = blockIdx.x % NS;
    int t = threadIdx.x; // 128
    __shared__ float sc[NS];
    __shared__ float at[NS];
    const float* qrow = qkv + q * 960 + h * HDM;
    if (t < NS) {
        const float* krow = qkv + t * 960 + EE + h * HDM;
        float s = 0.0f;
        for (int d = 0; d < HDM; ++d) s += qrow[d] * krow[d];
        sc[t] = s * 0.1118033988749895f; // 1/sqrt(80)
    }
    __syncthreads();
    float m = -1e30f;
    for (int s2 = 0; s2 < NS; ++s2) m = fmaxf(m, sc[s2]);
    float sum = 0.0f;
    for (int s2 = 0; s2 < NS; ++s2) sum += expf(sc[s2] - m);
    __syncthreads();
    if (t < NS) at[t] = expf(sc[t] - m) / sum;
    __syncthreads();
    if (t < HDM) {
        float acc = 0.0f;
        for (int s2 = 0; s2 < NS; ++s2) acc += at[s2] * qkv[s2 * 960 + 2 * EE + h * HDM + t];
        o[q * EE + h * HDM + t] = acc;
    }
}

// ---------------- attended = 0.5*(o @ W_out^T + b) ----------------
__global__ void k_proj(const float* __restrict__ o, const float* __restrict__ W,
                       const float* __restrict__ b, float* __restrict__ outp) {
    int idx = blockIdx.x * 256 + threadIdx.x;
    if (idx >= NS * EE) return;
    int i = idx / EE, c = idx % EE;
    const float4* orow = (const float4*)(o + i * EE);
    const float4* wr = (const float4*)(W + (size_t)c * EE);
    float acc = b[c];
    for (int k = 0; k < 80; ++k) {
        float4 a = orow[k], w = wr[k];
        acc += a.x * w.x + a.y * w.y + a.z * w.z + a.w * w.w;
    }
    outp[idx] = 0.5f * acc;
}

// ---------------- quantum pair MLP (one wave per pair) ----------------
__global__ void k_ent(const float* __restrict__ q_real,
                      const float* __restrict__ W1, const float* __restrict__ b1,
                      const float* __restrict__ W2, const float* __restrict__ b2,
                      float* __restrict__ ent_scaled) {
    int p = blockIdx.x;
    int i = 0, rem = p;
    while (rem >= 26 - i) { rem -= 26 - i; ++i; }
    int j = i + 1 + rem;
    int t = threadIdx.x; // 64
    __shared__ float comb[128];
    __shared__ float hid[64];
    float qa = q_real[i * CC + t];
    float qb = q_real[j * CC + t];
    float sa = qa, sb = qb;
    for (int off = 32; off; off >>= 1) { sa += __shfl_xor(sa, off); sb += __shfl_xor(sb, off); }
    float coupling = expf(-fabsf(sa - sb) / (500.0f + 1e-6f));
    comb[t] = qa; comb[64 + t] = qb;
    __syncthreads();
    float hs = b1[t];
    for (int ii = 0; ii < 128; ++ii) hs += comb[ii] * W1[ii * 64 + t];
    hid[t] = fmaxf(hs, 0.0f);
    __syncthreads();
    float e = b2[t];
    for (int k = 0; k < 64; ++k) e += hid[k] * W2[k * 64 + t];
    ent_scaled[p * 64 + t] = e * coupling;
}

__global__ void k_avg(const float* __restrict__ ent_scaled, float* __restrict__ avg) {
    int t = threadIdx.x; // 64
    float s = 0.0f;
    for (int p = 0; p < NPAIR; ++p) s += ent_scaled[p * 64 + t];
    avg[t] = s / (float)NPAIR;
}

__global__ void k_measured(const float* __restrict__ q_real, const float* __restrict__ q_imag,
                           const float* __restrict__ avg, const float* __restrict__ W,
                           const float* __restrict__ b, float* __restrict__ out) {
    int idx = blockIdx.x * 256 + threadIdx.x;
    if (idx >= NS * EE) return;
    int i = idx / EE, c = idx % EE;
    float acc = b[c];
    for (int k = 0; k < 64; ++k) {
        float a = avg[k];
        acc += (q_real[i * 64 + k] + a) * W[k * EE + c];
        acc += (q_imag[i * 64 + k] + a) * W[(64 + k) * EE + c];
    }
    out[idx] = acc;
}

// ---------------- the big one: mid agg partial (466 MB stream) ----------------
__global__ void k_mid_agg_partial(const float* __restrict__ W, const float* __restrict__ leaf,
                                  float* __restrict__ partial) {
    int n = blockIdx.x / SPLIT_MID;
    int s = blockIdx.x % SPLIT_MID;
    int t = threadIdx.x; // 128, j4 = t (active < 100)
    const float* c = leaf + n * 10800 + s * ROWS_MID;
    const float4* Wr = (const float4*)(W + (size_t)n * 10800 * 400) + (size_t)(s * ROWS_MID) * 100;
    if (t < 100) {
        float4 acc = make_float4(0.f, 0.f, 0.f, 0.f);
        #pragma unroll 4
        for (int r = 0; r < ROWS_MID; ++r) {
            float cv = c[r];
            float4 w = Wr[(size_t)r * 100 + t];
            acc.x += cv * w.x; acc.y += cv * w.y; acc.z += cv * w.z; acc.w += cv * w.w;
        }
        ((float4*)(partial + (size_t)blockIdx.x * 400))[t] = acc;
    }
}

// ---------------- mid reduce + update MLP, writes cf = new_mid flat ----------------
__global__ void k_mid_up(const float* __restrict__ partial, const float* __restrict__ agg_b,
                         const float* __restrict__ mid_states,
                         const float* __restrict__ W1, const float* __restrict__ b1,
                         const float* __restrict__ W2, const float* __restrict__ b2,
                         float* __restrict__ cf) {
    int n = blockIdx.x;
    int t = threadIdx.x; // 128
    __shared__ float comb[800];
    __shared__ float hid[64];
    for (int j = t; j < 400; j += 128) {
        float a = agg_b[n * 400 + j];
        for (int s = 0; s < SPLIT_MID; ++s) a += partial[(size_t)(n * SPLIT_MID + s) * 400 + j];
        comb[400 + j] = a;
        comb[j] = mid_states[n * 400 + j];
    }
    __syncthreads();
    if (t < 64) {
        const float* w1 = W1 + (size_t)n * 800 * 64;
        float hs = b1[n * 64 + t];
        for (int i2 = 0; i2 < 800; ++i2) hs += comb[i2] * w1[i2 * 64 + t];
        hid[t] = fmaxf(hs, 0.0f);
    }
    __syncthreads();
    for (int j = t; j < 400; j += 128) {
        const float* w2 = W2 + (size_t)n * 64 * 400;
        float u = b2[n * 400 + j];
        for (int k = 0; k < 64; ++k) u += hid[k] * w2[k * 400 + j];
        cf[n * 400 + j] = mid_states[n * 400 + j] + u;
    }
}

// ---------------- root agg partial (17 MB stream) ----------------
__global__ void k_root_partial(const float* __restrict__ W, const float* __restrict__ cf,
                               float* __restrict__ partial) {
    int s = blockIdx.x;
    int t = threadIdx.x; // 128
    const float* c = cf + s * ROWS_ROOT;
    const float4* Wr = (const float4*)W + (size_t)(s * ROWS_ROOT) * 100;
    if (t < 100) {
        float4 acc = make_float4(0.f, 0.f, 0.f, 0.f);
        #pragma unroll 4
        for (int r = 0; r < ROWS_ROOT; ++r) {
            float cv = c[r];
            float4 w = Wr[(size_t)r * 100 + t];
            acc.x += cv * w.x; acc.y += cv * w.y; acc.z += cv * w.z; acc.w += cv * w.w;
        }
        ((float4*)(partial + (size_t)s * 400))[t] = acc;
    }
}

// ---------------- root reduce + update MLP -> d_out ----------------
__global__ void k_root(const float* __restrict__ partial, const float* __restrict__ agg_b,
                       const float* __restrict__ root_state,
                       const float* __restrict__ W1, const float* __restrict__ b1,
                       const float* __restrict__ W2, const float* __restrict__ b2,
                       float* __restrict__ out) {
    int t = threadIdx.x; // 128
    __shared__ float comb[800];
    __shared__ float hid[64];
    for (int j = t; j < 400; j += 128) {
        float a = agg_b[j];
        for (int s = 0; s < SPLIT_ROOT; ++s) a += partial[s * 400 + j];
        comb[400 + j] = a;
        comb[j] = root_state[j];
    }
    __syncthreads();
    if (t < 64) {
        float hs = b1[t];
        for (int i2 = 0; i2 < 800; ++i2) hs += comb[i2] * W1[i2 * 64 + t];
        hid[t] = fmaxf(hs, 0.0f);
    }
    __syncthreads();
    for (int j = t; j < 400; j += 128) {
        float u = b2[j];
        for (int k = 0; k < 64; ++k) u += hid[k] * W2[k * 400 + j];
        out[j] = root_state[j] + u;
    }
}

extern "C" void kernel_launch(void* const* d_in, const int* in_sizes, int n_in,
                              void* d_out, int out_size, void* d_ws, size_t ws_size,
                              hipStream_t stream) {
    const float* node       = (const float*)d_in[0];
    const float* hist       = (const float*)d_in[1];
    const float* gW         = (const float*)d_in[2];
    const float* gb         = (const float*)d_in[3];
    const float* mha_in_W   = (const float*)d_in[4];
    const float* mha_in_b   = (const float*)d_in[5];
    const float* mha_out_W  = (const float*)d_in[6];
    const float* mha_out_b  = (const float*)d_in[7];
    const float* q_real     = (const float*)d_in[8];
    const float* q_imag     = (const float*)d_in[9];
    const float* ent_W1     = (const float*)d_in[10];
    const float* ent_b1     = (const float*)d_in[11];
    const float* ent_W2     = (const float*)d_in[12];
    const float* ent_b2     = (const float*)d_in[13];
    const float* meas_W     = (const float*)d_in[14];
    const float* meas_b     = (const float*)d_in[15];
    const float* leaf       = (const float*)d_in[16];
    const float* mid_states = (const float*)d_in[17];
    const float* root_state = (const float*)d_in[18];
    const float* mid_agg_W  = (const float*)d_in[19];
    const float* mid_agg_b  = (const float*)d_in[20];
    const float* root_agg_W = (const float*)d_in[21];
    const float* root_agg_b = (const float*)d_in[22];
    const float* mid_up_W1  = (const float*)d_in[23];
    const float* mid_up_b1  = (const float*)d_in[24];
    const float* mid_up_W2  = (const float*)d_in[25];
    const float* mid_up_b2  = (const float*)d_in[26];
    const float* root_up_W1 = (const float*)d_in[27];
    const float* root_up_b1 = (const float*)d_in[28];
    const float* root_up_W2 = (const float*)d_in[29];
    const float* root_up_b2 = (const float*)d_in[30];

    float* ws          = (float*)d_ws;
    float* qkv         = ws + WS_QKV;
    float* o           = ws + WS_O;
    float* ent_scaled  = ws + WS_ENT;
    float* avg         = ws + WS_AVG;
    float* mid_partial = ws + WS_MIDP;
    float* cf          = ws + WS_CF;
    float* root_partial= ws + WS_ROOTP;

    float* out        = (float*)d_out;
    float* out_causal = out;            // 729
    float* out_att    = out + 729;      // 8640
    float* out_meas   = out + 9369;     // 8640
    float* out_root   = out + 18009;    // 400

    // Big stream first (dominates runtime)
    hipLaunchKernelGGL(k_mid_agg_partial, dim3(NS * SPLIT_MID), dim3(128), 0, stream,
                       mid_agg_W, leaf, mid_partial);

    // causal
    hipLaunchKernelGGL(k_granger, dim3(3), dim3(256), 0, stream, node, hist, gW, gb, out_causal);

    // MHA chain
    hipLaunchKernelGGL(k_qkv, dim3((NS * 960 + 255) / 256), dim3(256), 0, stream,
                       node, mha_in_W, mha_in_b, qkv);
    hipLaunchKernelGGL(k_attn, dim3(NH * NS), dim3(128), 0, stream, qkv, o);
    hipLaunchKernelGGL(k_proj, dim3((NS * EE + 255) / 256), dim3(256), 0, stream,
                       o, mha_out_W, mha_out_b, out_att);

    // quantum chain
    hipLaunchKernelGGL(k_ent, dim3(NPAIR), dim3(64), 0, stream,
                       q_real, ent_W1, ent_b1, ent_W2, ent_b2, ent_scaled);
    hipLaunchKernelGGL(k_avg, dim3(1), dim3(64), 0, stream, ent_scaled, avg);
    hipLaunchKernelGGL(k_measured, dim3((NS * EE + 255) / 256), dim3(256), 0, stream,
                       q_real, q_imag, avg, meas_W, meas_b, out_meas);

    // fractal chain
    hipLaunchKernelGGL(k_mid_up, dim3(NS), dim3(128), 0, stream,
                       mid_partial, mid_agg_b, mid_states,
                       mid_up_W1, mid_up_b1, mid_up_W2, mid_up_b2, cf);
    hipLaunchKernelGGL(k_root_partial, dim3(SPLIT_ROOT), dim3(128), 0, stream,
                       root_agg_W, cf, root_partial);
    hipLaunchKernelGGL(k_root, dim3(1), dim3(128), 0, stream,
                       root_partial, root_agg_b, root_state,
                       root_up_W1, root_up_b1, root_up_W2, root_up_b2, out_root);
}

// Round 2
// 179.876 us; speedup vs baseline: 2.2890x; 2.2890x over previous
//
#include <hip/hip_runtime.h>
#include <math.h>

// ---------------- geometry ----------------
#define SD 64
#define CC 64
#define EE 320
#define NH 4
#define HDM 80
#define FF 400
#define NS 27
#define NPAIR 351

// ws layout (floats)
#define WS_QKV   0                 // 27*960 = 25920
#define WS_O     25920             // 27*320 = 8640
#define WS_ENT   34560             // 351*64 = 22464
#define WS_AVG   57024             // 64
#define WS_MIDP  57088             // 729*2*400 = 583200
#define WS_CF    640288            // 10800
#define WS_ROOTP 651088            // 216*400 = 86400
// total 737488 floats ~ 2.95 MB

// ================= K1 (256 threads): mid_agg | granger | qkv | ent =================
// blocks: [0,729) agg, [729,732) granger, [732,834) qkv, [834,1010) ent

__device__ void dev_mid_agg(int blk, const float* __restrict__ W,
                            const float* __restrict__ leaf, float* __restrict__ partial) {
    int n = blk / 27, chunk = blk % 27;
    int t = threadIdx.x;
    if (t >= 200) return;
    int rp = t / 100, j4 = t % 100;          // rp in {0,1}
    const float* c = leaf + n * 10800 + chunk * 400;
    const float4* Wr = (const float4*)(W + (size_t)(n * 10800 + chunk * 400) * 400);
    float4 acc = make_float4(0.f, 0.f, 0.f, 0.f);
    #pragma unroll 8
    for (int rr = 0; rr < 200; ++rr) {
        int r = 2 * rr + rp;
        float cv = c[r];
        float4 w = Wr[(size_t)r * 100 + j4];
        acc.x += cv * w.x; acc.y += cv * w.y; acc.z += cv * w.z; acc.w += cv * w.w;
    }
    ((float4*)(partial + (size_t)(blk * 2 + rp) * 400))[j4] = acc;
}

__device__ void dev_granger(int blk, const float* __restrict__ x, const float* __restrict__ h,
                            const float* __restrict__ gW, const float* __restrict__ gb,
                            float* __restrict__ out) {
    int idx = blk * 256 + threadIdx.x;
    if (idx >= NS * NS) return;
    int i = idx / NS, j = idx % NS;
    const float* hr = h + j * 320;
    const float* xr = x + i * 320;
    float acc = gb[0];
    for (int k = 0; k < 320; ++k) acc += hr[k] * gW[k] + xr[k] * gW[320 + k];
    float sig = 1.0f / (1.0f + expf(-acc));
    out[idx] = (i == j) ? 0.0f : sig;
}

__device__ void dev_qkv(int blk, const float* __restrict__ x, const float* __restrict__ W,
                        const float* __restrict__ b, float* __restrict__ qkv) {
    int idx = blk * 256 + threadIdx.x;
    if (idx >= NS * 960) return;
    int i = idx / 960, c = idx % 960;
    const float4* xr = (const float4*)(x + i * 320);
    const float4* wr = (const float4*)(W + (size_t)c * 320);
    float acc = b[c];
    #pragma unroll 8
    for (int k = 0; k < 80; ++k) {
        float4 a = xr[k], w = wr[k];
        acc += a.x * w.x + a.y * w.y + a.z * w.z + a.w * w.w;
    }
    qkv[idx] = acc;
}

__device__ void dev_ent(int blk, const float* __restrict__ q_real,
                        const float* __restrict__ W1, const float* __restrict__ b1,
                        const float* __restrict__ W2, const float* __restrict__ b2,
                        float* __restrict__ ent_scaled) {
    __shared__ float comb[2][128];
    __shared__ float hid[2][64];
    int t = threadIdx.x;
    int sub = t >> 7, lt = t & 127;
    int p = blk * 2 + sub;
    bool pv = (p < NPAIR);
    bool valid = pv && (lt < 64);
    int i = 0, jj = 0;
    if (pv) {
        int rem = p;
        while (rem >= 26 - i) { rem -= 26 - i; ++i; }
        jj = i + 1 + rem;
    }
    float qa = 0.f, qb = 0.f;
    if (valid) { qa = q_real[i * CC + lt]; qb = q_real[jj * CC + lt]; }
    float sa = qa, sb = qb;
    #pragma unroll
    for (int off = 32; off; off >>= 1) { sa += __shfl_xor(sa, off); sb += __shfl_xor(sb, off); }
    float coupling = expf(-fabsf(sa - sb) / (500.0f + 1e-6f));
    if (valid) { comb[sub][lt] = qa; comb[sub][64 + lt] = qb; }
    __syncthreads();
    if (valid) {
        float hs = b1[lt];
        for (int ii = 0; ii < 128; ++ii) hs += comb[sub][ii] * W1[ii * 64 + lt];
        hid[sub][lt] = fmaxf(hs, 0.0f);
    }
    __syncthreads();
    if (valid) {
        float e = b2[lt];
        for (int k = 0; k < 64; ++k) e += hid[sub][k] * W2[k * 64 + lt];
        ent_scaled[p * 64 + lt] = e * coupling;
    }
}

__global__ __launch_bounds__(256) void k_stage1(
    const float* __restrict__ mid_agg_W, const float* __restrict__ leaf,
    const float* __restrict__ node, const float* __restrict__ hist,
    const float* __restrict__ gW, const float* __restrict__ gb,
    const float* __restrict__ mha_in_W, const float* __restrict__ mha_in_b,
    const float* __restrict__ q_real,
    const float* __restrict__ ent_W1, const float* __restrict__ ent_b1,
    const float* __restrict__ ent_W2, const float* __restrict__ ent_b2,
    float* __restrict__ mid_partial, float* __restrict__ out_causal,
    float* __restrict__ qkv, float* __restrict__ ent_scaled) {
    int blk = blockIdx.x;
    if (blk < 729)       dev_mid_agg(blk, mid_agg_W, leaf, mid_partial);
    else if (blk < 732)  dev_granger(blk - 729, node, hist, gW, gb, out_causal);
    else if (blk < 834)  dev_qkv(blk - 732, node, mha_in_W, mha_in_b, qkv);
    else                 dev_ent(blk - 834, q_real, ent_W1, ent_b1, ent_W2, ent_b2, ent_scaled);
}

// ================= K2 (512 threads): attn | avg | mid_up =================
// blocks: [0,108) attn, 108 avg, [109,136) mid_up

__device__ void dev_attn(int blk, const float* __restrict__ qkv, float* __restrict__ o) {
    int h = blk / NS, q = blk % NS;
    int t = threadIdx.x;
    __shared__ float sc[NS];
    __shared__ float at[NS];
    if (t < NS) {
        const float* qrow = qkv + q * 960 + h * HDM;
        const float* krow = qkv + t * 960 + EE + h * HDM;
        float s = 0.0f;
        for (int d = 0; d < HDM; ++d) s += qrow[d] * krow[d];
        sc[t] = s * 0.1118033988749895f;
    }
    __syncthreads();
    if (t < NS) {
        float m = -1e30f;
        for (int s2 = 0; s2 < NS; ++s2) m = fmaxf(m, sc[s2]);
        float sum = 0.0f;
        for (int s2 = 0; s2 < NS; ++s2) sum += expf(sc[s2] - m);
        at[t] = expf(sc[t] - m) / sum;
    }
    __syncthreads();
    if (t < HDM) {
        float acc = 0.0f;
        for (int s2 = 0; s2 < NS; ++s2) acc += at[s2] * qkv[s2 * 960 + 2 * EE + h * HDM + t];
        o[q * EE + h * HDM + t] = acc;
    }
}

__device__ void dev_avg(const float* __restrict__ ent_scaled, float* __restrict__ avg) {
    int t = threadIdx.x;
    if (t >= 64) return;
    float s = 0.0f;
    for (int p = 0; p < NPAIR; ++p) s += ent_scaled[p * 64 + t];
    avg[t] = s / (float)NPAIR;
}

__device__ void dev_mid_up(int n, const float* __restrict__ partial, const float* __restrict__ agg_b,
                           const float* __restrict__ mid_states,
                           const float* __restrict__ W1, const float* __restrict__ b1,
                           const float* __restrict__ W2, const float* __restrict__ b2,
                           float* __restrict__ cf) {
    __shared__ float comb[800];
    __shared__ float hp[512];
    __shared__ float hid[64];
    int t = threadIdx.x;
    if (t < 400) {
        float a = agg_b[n * 400 + t];
        const float* pp = partial + (size_t)(n * 54) * 400 + t;
        #pragma unroll 6
        for (int s = 0; s < 54; ++s) a += pp[s * 400];
        comb[400 + t] = a;
        comb[t] = mid_states[n * 400 + t];
    }
    __syncthreads();
    {
        int kk = t >> 6, h = t & 63;
        const float* w1 = W1 + (size_t)n * 800 * 64;
        float hs = 0.0f;
        #pragma unroll 4
        for (int i2 = kk * 100; i2 < kk * 100 + 100; ++i2) hs += comb[i2] * w1[i2 * 64 + h];
        hp[t] = hs;
    }
    __syncthreads();
    if (t < 64) {
        float hs = b1[n * 64 + t];
        #pragma unroll
        for (int kk = 0; kk < 8; ++kk) hs += hp[kk * 64 + t];
        hid[t] = fmaxf(hs, 0.0f);
    }
    __syncthreads();
    if (t < 400) {
        const float* w2 = W2 + (size_t)n * 64 * 400;
        float u = b2[n * 400 + t];
        #pragma unroll 8
        for (int k = 0; k < 64; ++k) u += hid[k] * w2[k * 400 + t];
        cf[n * 400 + t] = mid_states[n * 400 + t] + u;
    }
}

__global__ __launch_bounds__(512) void k_stage2(
    const float* __restrict__ qkv, float* __restrict__ o,
    const float* __restrict__ ent_scaled, float* __restrict__ avg,
    const float* __restrict__ mid_partial, const float* __restrict__ mid_agg_b,
    const float* __restrict__ mid_states,
    const float* __restrict__ mid_up_W1, const float* __restrict__ mid_up_b1,
    const float* __restrict__ mid_up_W2, const float* __restrict__ mid_up_b2,
    float* __restrict__ cf) {
    int blk = blockIdx.x;
    if (blk < 108)       dev_attn(blk, qkv, o);
    else if (blk == 108) dev_avg(ent_scaled, avg);
    else                 dev_mid_up(blk - 109, mid_partial, mid_agg_b, mid_states,
                                    mid_up_W1, mid_up_b1, mid_up_W2, mid_up_b2, cf);
}

// ================= K3 (512 threads): proj | measured | root_partial =================
// blocks: [0,17) proj, [17,34) measured, [34,88) root_partial

__device__ void dev_proj(int blk, const float* __restrict__ o, const float* __restrict__ W,
                         const float* __restrict__ b, float* __restrict__ outp) {
    int idx = blk * 512 + threadIdx.x;
    if (idx >= NS * EE) return;
    int i = idx / EE, c = idx % EE;
    const float4* orow = (const float4*)(o + i * EE);
    const float4* wr = (const float4*)(W + (size_t)c * EE);
    float acc = b[c];
    #pragma unroll 8
    for (int k = 0; k < 80; ++k) {
        float4 a = orow[k], w = wr[k];
        acc += a.x * w.x + a.y * w.y + a.z * w.z + a.w * w.w;
    }
    outp[idx] = 0.5f * acc;
}

__device__ void dev_measured(int blk, const float* __restrict__ q_real, const float* __restrict__ q_imag,
                             const float* __restrict__ avg, const float* __restrict__ W,
                             const float* __restrict__ b, float* __restrict__ out) {
    int idx = blk * 512 + threadIdx.x;
    if (idx >= NS * EE) return;
    int i = idx / EE, c = idx % EE;
    float acc = b[c];
    #pragma unroll 8
    for (int k = 0; k < 64; ++k) {
        float a = avg[k];
        acc += (q_real[i * 64 + k] + a) * W[k * EE + c];
        acc += (q_imag[i * 64 + k] + a) * W[(64 + k) * EE + c];
    }
    out[idx] = acc;
}

__device__ void dev_root_partial(int chunk, const float* __restrict__ W, const float* __restrict__ cf,
                                 float* __restrict__ partial) {
    int t = threadIdx.x;
    int rg = t >> 7, tt = t & 127;
    if (tt >= 100) return;
    int row0 = chunk * 200 + rg * 50;
    const float* c = cf + row0;
    const float4* Wr = (const float4*)W + (size_t)row0 * 100;
    float4 acc = make_float4(0.f, 0.f, 0.f, 0.f);
    #pragma unroll 10
    for (int r = 0; r < 50; ++r) {
        float cv = c[r];
        float4 w = Wr[(size_t)r * 100 + tt];
        acc.x += cv * w.x; acc.y += cv * w.y; acc.z += cv * w.z; acc.w += cv * w.w;
    }
    ((float4*)(partial + (size_t)(chunk * 4 + rg) * 400))[tt] = acc;
}

__global__ __launch_bounds__(512) void k_stage3(
    const float* __restrict__ o, const float* __restrict__ mha_out_W,
    const float* __restrict__ mha_out_b, float* __restrict__ out_att,
    const float* __restrict__ q_real, const float* __restrict__ q_imag,
    const float* __restrict__ avg, const float* __restrict__ meas_W,
    const float* __restrict__ meas_b, float* __restrict__ out_meas,
    const float* __restrict__ root_agg_W, const float* __restrict__ cf,
    float* __restrict__ root_partial) {
    int blk = blockIdx.x;
    if (blk < 17)       dev_proj(blk, o, mha_out_W, mha_out_b, out_att);
    else if (blk < 34)  dev_measured(blk - 17, q_real, q_imag, avg, meas_W, meas_b, out_meas);
    else                dev_root_partial(blk - 34, root_agg_W, cf, root_partial);
}

// ================= K4 (512 threads, 1 block): root reduce + update =================
__global__ __launch_bounds__(512) void k_root(
    const float* __restrict__ partial, const float* __restrict__ agg_b,
    const float* __restrict__ root_state,
    const float* __restrict__ W1, const float* __restrict__ b1,
    const float* __restrict__ W2, const float* __restrict__ b2,
    float* __restrict__ out) {
    __shared__ float comb[800];
    __shared__ float hp[512];
    __shared__ float hid[64];
    int t = threadIdx.x;
    if (t < 400) {
        float a = agg_b[t];
        const float* pp = partial + t;
        #pragma unroll 8
        for (int s = 0; s < 216; ++s) a += pp[s * 400];
        comb[400 + t] = a;
        comb[t] = root_state[t];
    }
    __syncthreads();
    {
        int kk = t >> 6, h = t & 63;
        float hs = 0.0f;
        #pragma unroll 4
        for (int i2 = kk * 100; i2 < kk * 100 + 100; ++i2) hs += comb[i2] * W1[i2 * 64 + h];
        hp[t] = hs;
    }
    __syncthreads();
    if (t < 64) {
        float hs = b1[t];
        #pragma unroll
        for (int kk = 0; kk < 8; ++kk) hs += hp[kk * 64 + t];
        hid[t] = fmaxf(hs, 0.0f);
    }
    __syncthreads();
    if (t < 400) {
        float u = b2[t];
        #pragma unroll 8
        for (int k = 0; k < 64; ++k) u += hid[k] * W2[k * 400 + t];
        out[t] = root_state[t] + u;
    }
}

extern "C" void kernel_launch(void* const* d_in, const int* in_sizes, int n_in,
                              void* d_out, int out_size, void* d_ws, size_t ws_size,
                              hipStream_t stream) {
    const float* node       = (const float*)d_in[0];
    const float* hist       = (const float*)d_in[1];
    const float* gW         = (const float*)d_in[2];
    const float* gb         = (const float*)d_in[3];
    const float* mha_in_W   = (const float*)d_in[4];
    const float* mha_in_b   = (const float*)d_in[5];
    const float* mha_out_W  = (const float*)d_in[6];
    const float* mha_out_b  = (const float*)d_in[7];
    const float* q_real     = (const float*)d_in[8];
    const float* q_imag     = (const float*)d_in[9];
    const float* ent_W1     = (const float*)d_in[10];
    const float* ent_b1     = (const float*)d_in[11];
    const float* ent_W2     = (const float*)d_in[12];
    const float* ent_b2     = (const float*)d_in[13];
    const float* meas_W     = (const float*)d_in[14];
    const float* meas_b     = (const float*)d_in[15];
    const float* leaf       = (const float*)d_in[16];
    const float* mid_states = (const float*)d_in[17];
    const float* root_state = (const float*)d_in[18];
    const float* mid_agg_W  = (const float*)d_in[19];
    const float* mid_agg_b  = (const float*)d_in[20];
    const float* root_agg_W = (const float*)d_in[21];
    const float* root_agg_b = (const float*)d_in[22];
    const float* mid_up_W1  = (const float*)d_in[23];
    const float* mid_up_b1  = (const float*)d_in[24];
    const float* mid_up_W2  = (const float*)d_in[25];
    const float* mid_up_b2  = (const float*)d_in[26];
    const float* root_up_W1 = (const float*)d_in[27];
    const float* root_up_b1 = (const float*)d_in[28];
    const float* root_up_W2 = (const float*)d_in[29];
    const float* root_up_b2 = (const float*)d_in[30];

    float* ws          = (float*)d_ws;
    float* qkv         = ws + WS_QKV;
    float* o           = ws + WS_O;
    float* ent_scaled  = ws + WS_ENT;
    float* avg         = ws + WS_AVG;
    float* mid_partial = ws + WS_MIDP;
    float* cf          = ws + WS_CF;
    float* root_part   = ws + WS_ROOTP;

    float* out        = (float*)d_out;
    float* out_causal = out;            // 729
    float* out_att    = out + 729;      // 8640
    float* out_meas   = out + 9369;     // 8640
    float* out_root   = out + 18009;    // 400

    hipLaunchKernelGGL(k_stage1, dim3(1010), dim3(256), 0, stream,
                       mid_agg_W, leaf, node, hist, gW, gb, mha_in_W, mha_in_b,
                       q_real, ent_W1, ent_b1, ent_W2, ent_b2,
                       mid_partial, out_causal, qkv, ent_scaled);

    hipLaunchKernelGGL(k_stage2, dim3(136), dim3(512), 0, stream,
                       qkv, o, ent_scaled, avg, mid_partial, mid_agg_b, mid_states,
                       mid_up_W1, mid_up_b1, mid_up_W2, mid_up_b2, cf);

    hipLaunchKernelGGL(k_stage3, dim3(88), dim3(512), 0, stream,
                       o, mha_out_W, mha_out_b, out_att,
                       q_real, q_imag, avg, meas_W, meas_b, out_meas,
                       root_agg_W, cf, root_part);

    hipLaunchKernelGGL(k_root, dim3(1), dim3(512), 0, stream,
                       root_part, root_agg_b, root_state,
                       root_up_W1, root_up_b1, root_up_W2, root_up_b2, out_root);
}

// Round 4
// 143.739 us; speedup vs baseline: 2.8645x; 1.2514x over previous
//
#include <hip/hip_runtime.h>
#include <math.h>

typedef float v4f __attribute__((ext_vector_type(4)));

// ---------------- geometry ----------------
#define SD 64
#define CC 64
#define EE 320
#define NH 4
#define HDM 80
#define NS 27
#define NPAIR 351

// stage1 agg tiling: per mid node 10800 rows -> 54 chunks of 200 rows
#define NCHUNK 54
#define AGG_BLKS (27 * NCHUNK)   // 1458

// ws layout (floats)
#define WS_QKV   0                        // 27*960 = 25920
#define WS_O     25920                    // 8640
#define WS_ENT   34560                    // 351*64 = 22464
#define WS_AVG   57024                    // 64
#define WS_MIDP  57088                    // 1458*2*400 = 1166400
#define WS_CF    1223488                  // 10800
#define WS_ROOTP 1234288                  // 108*400 = 43200
// total ~1277488 floats ~ 5.1 MB

// ================= K1 (256 threads): mid_agg | granger | qkv | ent =================
// blocks: [0,1458) agg, [1458,1461) granger, [1461,1563) qkv, [1563,1739) ent

__device__ void dev_mid_agg(int blk, const float* __restrict__ W,
                            const float* __restrict__ leaf, float* __restrict__ partial) {
    int n = blk / NCHUNK, chunk = blk % NCHUNK;
    int t = threadIdx.x;
    if (t >= 200) return;
    int rp = t / 100, j4 = t % 100;          // rp in {0,1}
    const float* c = leaf + n * 10800 + chunk * 200;
    const v4f* Wr = (const v4f*)(W + (size_t)(n * 10800 + chunk * 200) * 400);
    v4f acc = (v4f)(0.0f);
    #pragma unroll 16
    for (int rr = 0; rr < 100; ++rr) {
        int r = 2 * rr + rp;
        float cv = c[r];
        v4f w = __builtin_nontemporal_load(&Wr[(size_t)r * 100 + j4]);
        acc += cv * w;
    }
    ((v4f*)(partial + (size_t)(blk * 2 + rp) * 400))[j4] = acc;
}

__device__ void dev_granger(int blk, const float* __restrict__ x, const float* __restrict__ h,
                            const float* __restrict__ gW, const float* __restrict__ gb,
                            float* __restrict__ out) {
    int idx = blk * 256 + threadIdx.x;
    if (idx >= NS * NS) return;
    int i = idx / NS, j = idx % NS;
    const float* hr = h + j * 320;
    const float* xr = x + i * 320;
    float acc = gb[0];
    for (int k = 0; k < 320; ++k) acc += hr[k] * gW[k] + xr[k] * gW[320 + k];
    float sig = 1.0f / (1.0f + expf(-acc));
    out[idx] = (i == j) ? 0.0f : sig;
}

__device__ void dev_qkv(int blk, const float* __restrict__ x, const float* __restrict__ W,
                        const float* __restrict__ b, float* __restrict__ qkv) {
    int idx = blk * 256 + threadIdx.x;
    if (idx >= NS * 960) return;
    int i = idx / 960, c = idx % 960;
    const float4* xr = (const float4*)(x + i * 320);
    const float4* wr = (const float4*)(W + (size_t)c * 320);
    float acc = b[c];
    #pragma unroll 8
    for (int k = 0; k < 80; ++k) {
        float4 a = xr[k], w = wr[k];
        acc += a.x * w.x + a.y * w.y + a.z * w.z + a.w * w.w;
    }
    qkv[idx] = acc;
}

__device__ void dev_ent(int blk, const float* __restrict__ q_real,
                        const float* __restrict__ W1, const float* __restrict__ b1,
                        const float* __restrict__ W2, const float* __restrict__ b2,
                        float* __restrict__ ent_scaled) {
    __shared__ float comb[2][128];
    __shared__ float hid[2][64];
    int t = threadIdx.x;
    int sub = t >> 7, lt = t & 127;
    int p = blk * 2 + sub;
    bool pv = (p < NPAIR);
    bool valid = pv && (lt < 64);
    int i = 0, jj = 0;
    if (pv) {
        int rem = p;
        while (rem >= 26 - i) { rem -= 26 - i; ++i; }
        jj = i + 1 + rem;
    }
    float qa = 0.f, qb = 0.f;
    if (valid) { qa = q_real[i * CC + lt]; qb = q_real[jj * CC + lt]; }
    float sa = qa, sb = qb;
    #pragma unroll
    for (int off = 32; off; off >>= 1) { sa += __shfl_xor(sa, off); sb += __shfl_xor(sb, off); }
    float coupling = expf(-fabsf(sa - sb) / (500.0f + 1e-6f));
    if (valid) { comb[sub][lt] = qa; comb[sub][64 + lt] = qb; }
    __syncthreads();
    if (valid) {
        float hs = b1[lt];
        for (int ii = 0; ii < 128; ++ii) hs += comb[sub][ii] * W1[ii * 64 + lt];
        hid[sub][lt] = fmaxf(hs, 0.0f);
    }
    __syncthreads();
    if (valid) {
        float e = b2[lt];
        for (int k = 0; k < 64; ++k) e += hid[sub][k] * W2[k * 64 + lt];
        ent_scaled[p * 64 + lt] = e * coupling;
    }
}

__global__ __launch_bounds__(256) void k_stage1(
    const float* __restrict__ mid_agg_W, const float* __restrict__ leaf,
    const float* __restrict__ node, const float* __restrict__ hist,
    const float* __restrict__ gW, const float* __restrict__ gb,
    const float* __restrict__ mha_in_W, const float* __restrict__ mha_in_b,
    const float* __restrict__ q_real,
    const float* __restrict__ ent_W1, const float* __restrict__ ent_b1,
    const float* __restrict__ ent_W2, const float* __restrict__ ent_b2,
    float* __restrict__ mid_partial, float* __restrict__ out_causal,
    float* __restrict__ qkv, float* __restrict__ ent_scaled) {
    int blk = blockIdx.x;
    if (blk < AGG_BLKS)          dev_mid_agg(blk, mid_agg_W, leaf, mid_partial);
    else if (blk < AGG_BLKS + 3) dev_granger(blk - AGG_BLKS, node, hist, gW, gb, out_causal);
    else if (blk < AGG_BLKS + 105) dev_qkv(blk - AGG_BLKS - 3, node, mha_in_W, mha_in_b, qkv);
    else                         dev_ent(blk - AGG_BLKS - 105, q_real, ent_W1, ent_b1, ent_W2, ent_b2, ent_scaled);
}

// ================= K2 (512 threads): attn | avg | mid_up =================
// blocks: [0,108) attn, 108 avg, [109,136) mid_up

__device__ void dev_attn(int blk, const float* __restrict__ qkv, float* __restrict__ o) {
    int h = blk / NS, q = blk % NS;
    int t = threadIdx.x;
    __shared__ float sc[NS];
    __shared__ float at[NS];
    if (t < NS) {
        const float* qrow = qkv + q * 960 + h * HDM;
        const float* krow = qkv + t * 960 + EE + h * HDM;
        float s = 0.0f;
        for (int d = 0; d < HDM; ++d) s += qrow[d] * krow[d];
        sc[t] = s * 0.1118033988749895f;
    }
    __syncthreads();
    if (t < NS) {
        float m = -1e30f;
        for (int s2 = 0; s2 < NS; ++s2) m = fmaxf(m, sc[s2]);
        float sum = 0.0f;
        for (int s2 = 0; s2 < NS; ++s2) sum += expf(sc[s2] - m);
        at[t] = expf(sc[t] - m) / sum;
    }
    __syncthreads();
    if (t < HDM) {
        float acc = 0.0f;
        for (int s2 = 0; s2 < NS; ++s2) acc += at[s2] * qkv[s2 * 960 + 2 * EE + h * HDM + t];
        o[q * EE + h * HDM + t] = acc;
    }
}

__device__ void dev_avg(const float* __restrict__ ent_scaled, float* __restrict__ avg) {
    __shared__ float aacc[8][64];
    int t = threadIdx.x;
    int col = t & 63, grp = t >> 6;   // 8 groups
    float s = 0.0f;
    for (int p = grp; p < NPAIR; p += 8) s += ent_scaled[p * 64 + col];
    aacc[grp][col] = s;
    __syncthreads();
    if (t < 64) {
        float a = 0.0f;
        #pragma unroll
        for (int g = 0; g < 8; ++g) a += aacc[g][t];
        avg[t] = a / (float)NPAIR;
    }
}

// shared helper: coalesced float4 GEMV pair (800->64 relu, 64->400) with LDS reduces
__device__ void dev_up_mlp(const float* __restrict__ comb /*LDS 800*/,
                           const float* __restrict__ W1, const float* __restrict__ b1,
                           const float* __restrict__ W2, const float* __restrict__ b2,
                           const float* __restrict__ base, float* __restrict__ outp,
                           float* __restrict__ s4f /*LDS 2048*/, float* __restrict__ hid /*LDS 64*/) {
    int t = threadIdx.x;
    // W1: flat [800*64] as float4: idx = t + 512*it, i = idx/16, h0 = (idx%16)*4 (const per t)
    {
        const float4* W1f = (const float4*)W1;
        int i0 = t >> 4;
        float4 a4 = make_float4(0.f, 0.f, 0.f, 0.f);
        #pragma unroll
        for (int it = 0; it < 25; ++it) {
            float4 w = W1f[t + 512 * it];
            float cv = comb[i0 + 32 * it];
            a4.x += cv * w.x; a4.y += cv * w.y; a4.z += cv * w.z; a4.w += cv * w.w;
        }
        ((float4*)s4f)[t] = a4;
    }
    __syncthreads();
    if (t < 64) {
        float hs = b1[t];
        int r = t >> 2, c = t & 3;
        #pragma unroll 8
        for (int g = 0; g < 32; ++g) hs += s4f[(r + 16 * g) * 4 + c];
        hid[t] = fmaxf(hs, 0.0f);
    }
    __syncthreads();
    // W2: [64][400] as float4 rows of 100
    __shared__ float racc[4][400];
    if (t < 400) {
        int g = t / 100, j4 = t % 100;
        const float4* W2f = (const float4*)W2;
        float4 a4 = make_float4(0.f, 0.f, 0.f, 0.f);
        #pragma unroll
        for (int m = 0; m < 16; ++m) {
            int k = g + 4 * m;
            float4 w = W2f[k * 100 + j4];
            float hv = hid[k];
            a4.x += hv * w.x; a4.y += hv * w.y; a4.z += hv * w.z; a4.w += hv * w.w;
        }
        ((float4*)&racc[g][0])[j4] = a4;
    }
    __syncthreads();
    if (t < 400) {
        float u = b2[t];
        #pragma unroll
        for (int g = 0; g < 4; ++g) u += racc[g][t];
        outp[t] = base[t] + u;
    }
}

__device__ void dev_mid_up(int n, const float* __restrict__ partial, const float* __restrict__ agg_b,
                           const float* __restrict__ mid_states,
                           const float* __restrict__ W1, const float* __restrict__ b1,
                           const float* __restrict__ W2, const float* __restrict__ b2,
                           float* __restrict__ cf) {
    __shared__ float comb[800];
    __shared__ float s4f[2048];
    __shared__ float hid[64];
    int t = threadIdx.x;
    if (t < 400) {
        float a = agg_b[n * 400 + t];
        const float* pp = partial + (size_t)(n * NCHUNK * 2) * 400 + t;
        #pragma unroll 12
        for (int s = 0; s < NCHUNK * 2; ++s) a += pp[s * 400];
        comb[400 + t] = a;
        comb[t] = mid_states[n * 400 + t];
    }
    __syncthreads();
    dev_up_mlp(comb, W1 + (size_t)n * 51200, b1 + n * 64, W2 + (size_t)n * 25600, b2 + n * 400,
               mid_states + n * 400, cf + n * 400, s4f, hid);
}

__global__ __launch_bounds__(512) void k_stage2(
    const float* __restrict__ qkv, float* __restrict__ o,
    const float* __restrict__ ent_scaled, float* __restrict__ avg,
    const float* __restrict__ mid_partial, const float* __restrict__ mid_agg_b,
    const float* __restrict__ mid_states,
    const float* __restrict__ mid_up_W1, const float* __restrict__ mid_up_b1,
    const float* __restrict__ mid_up_W2, const float* __restrict__ mid_up_b2,
    float* __restrict__ cf) {
    int blk = blockIdx.x;
    if (blk < 108)       dev_attn(blk, qkv, o);
    else if (blk == 108) dev_avg(ent_scaled, avg);
    else                 dev_mid_up(blk - 109, mid_partial, mid_agg_b, mid_states,
                                    mid_up_W1, mid_up_b1, mid_up_W2, mid_up_b2, cf);
}

// ================= K3 (512 threads): proj | measured | root_partial =================
// blocks: [0,17) proj, [17,34) measured, [34,142) root_partial (108 chunks of 100 rows)

__device__ void dev_proj(int blk, const float* __restrict__ o, const float* __restrict__ W,
                         const float* __restrict__ b, float* __restrict__ outp) {
    int idx = blk * 512 + threadIdx.x;
    if (idx >= NS * EE) return;
    int i = idx / EE, c = idx % EE;
    const float4* orow = (const float4*)(o + i * EE);
    const float4* wr = (const float4*)(W + (size_t)c * EE);
    float acc = b[c];
    #pragma unroll 8
    for (int k = 0; k < 80; ++k) {
        float4 a = orow[k], w = wr[k];
        acc += a.x * w.x + a.y * w.y + a.z * w.z + a.w * w.w;
    }
    outp[idx] = 0.5f * acc;
}

__device__ void dev_measured(int blk, const float* __restrict__ q_real, const float* __restrict__ q_imag,
                             const float* __restrict__ avg, const float* __restrict__ W,
                             const float* __restrict__ b, float* __restrict__ out) {
    int idx = blk * 512 + threadIdx.x;
    if (idx >= NS * EE) return;
    int i = idx / EE, c = idx % EE;
    float acc = b[c];
    #pragma unroll 8
    for (int k = 0; k < 64; ++k) {
        float a = avg[k];
        acc += (q_real[i * 64 + k] + a) * W[k * EE + c];
        acc += (q_imag[i * 64 + k] + a) * W[(64 + k) * EE + c];
    }
    out[idx] = acc;
}

__device__ void dev_root_partial(int chunk, const float* __restrict__ W, const float* __restrict__ cf,
                                 float* __restrict__ partial) {
    __shared__ float racc[5][400];
    int t = threadIdx.x;
    int rp = t / 100, j4 = t % 100;   // rp in {0..4}, 500 active + 12 idle
    if (rp < 5) {
        const float* c = cf + chunk * 100;
        const v4f* Wr = (const v4f*)W + (size_t)(chunk * 100) * 100;
        v4f acc = (v4f)(0.0f);
        #pragma unroll
        for (int rr = 0; rr < 20; ++rr) {
            int r = 5 * rr + rp;
            float cv = c[r];
            v4f w = __builtin_nontemporal_load(&Wr[(size_t)r * 100 + j4]);
            acc += cv * w;
        }
        racc[rp][j4 * 4 + 0] = acc.x;
        racc[rp][j4 * 4 + 1] = acc.y;
        racc[rp][j4 * 4 + 2] = acc.z;
        racc[rp][j4 * 4 + 3] = acc.w;
    }
    __syncthreads();
    if (t < 400) {
        float a = 0.0f;
        #pragma unroll
        for (int g = 0; g < 5; ++g) a += racc[g][t];
        partial[chunk * 400 + t] = a;
    }
}

__global__ __launch_bounds__(512) void k_stage3(
    const float* __restrict__ o, const float* __restrict__ mha_out_W,
    const float* __restrict__ mha_out_b, float* __restrict__ out_att,
    const float* __restrict__ q_real, const float* __restrict__ q_imag,
    const float* __restrict__ avg, const float* __restrict__ meas_W,
    const float* __restrict__ meas_b, float* __restrict__ out_meas,
    const float* __restrict__ root_agg_W, const float* __restrict__ cf,
    float* __restrict__ root_partial) {
    int blk = blockIdx.x;
    if (blk < 17)       dev_proj(blk, o, mha_out_W, mha_out_b, out_att);
    else if (blk < 34)  dev_measured(blk - 17, q_real, q_imag, avg, meas_W, meas_b, out_meas);
    else                dev_root_partial(blk - 34, root_agg_W, cf, root_partial);
}

// ================= K4 (512 threads, 1 block): root reduce + update =================
__global__ __launch_bounds__(512) void k_root(
    const float* __restrict__ partial, const float* __restrict__ agg_b,
    const float* __restrict__ root_state,
    const float* __restrict__ W1, const float* __restrict__ b1,
    const float* __restrict__ W2, const float* __restrict__ b2,
    float* __restrict__ out) {
    __shared__ float comb[800];
    __shared__ float s4f[2048];
    __shared__ float hid[64];
    int t = threadIdx.x;
    if (t < 400) {
        float a = agg_b[t];
        const float* pp = partial + t;
        #pragma unroll 12
        for (int s = 0; s < 108; ++s) a += pp[s * 400];
        comb[400 + t] = a;
        comb[t] = root_state[t];
    }
    __syncthreads();
    dev_up_mlp(comb, W1, b1, W2, b2, root_state, out, s4f, hid);
}

extern "C" void kernel_launch(void* const* d_in, const int* in_sizes, int n_in,
                              void* d_out, int out_size, void* d_ws, size_t ws_size,
                              hipStream_t stream) {
    const float* node       = (const float*)d_in[0];
    const float* hist       = (const float*)d_in[1];
    const float* gW         = (const float*)d_in[2];
    const float* gb         = (const float*)d_in[3];
    const float* mha_in_W   = (const float*)d_in[4];
    const float* mha_in_b   = (const float*)d_in[5];
    const float* mha_out_W  = (const float*)d_in[6];
    const float* mha_out_b  = (const float*)d_in[7];
    const float* q_real     = (const float*)d_in[8];
    const float* q_imag     = (const float*)d_in[9];
    const float* ent_W1     = (const float*)d_in[10];
    const float* ent_b1     = (const float*)d_in[11];
    const float* ent_W2     = (const float*)d_in[12];
    const float* ent_b2     = (const float*)d_in[13];
    const float* meas_W     = (const float*)d_in[14];
    const float* meas_b     = (const float*)d_in[15];
    const float* leaf       = (const float*)d_in[16];
    const float* mid_states = (const float*)d_in[17];
    const float* root_state = (const float*)d_in[18];
    const float* mid_agg_W  = (const float*)d_in[19];
    const float* mid_agg_b  = (const float*)d_in[20];
    const float* root_agg_W = (const float*)d_in[21];
    const float* root_agg_b = (const float*)d_in[22];
    const float* mid_up_W1  = (const float*)d_in[23];
    const float* mid_up_b1  = (const float*)d_in[24];
    const float* mid_up_W2  = (const float*)d_in[25];
    const float* mid_up_b2  = (const float*)d_in[26];
    const float* root_up_W1 = (const float*)d_in[27];
    const float* root_up_b1 = (const float*)d_in[28];
    const float* root_up_W2 = (const float*)d_in[29];
    const float* root_up_b2 = (const float*)d_in[30];

    float* ws          = (float*)d_ws;
    float* qkv         = ws + WS_QKV;
    float* o           = ws + WS_O;
    float* ent_scaled  = ws + WS_ENT;
    float* avg         = ws + WS_AVG;
    float* mid_partial = ws + WS_MIDP;
    float* cf          = ws + WS_CF;
    float* root_part   = ws + WS_ROOTP;

    float* out        = (float*)d_out;
    float* out_causal = out;            // 729
    float* out_att    = out + 729;      // 8640
    float* out_meas   = out + 9369;     // 8640
    float* out_root   = out + 18009;    // 400

    hipLaunchKernelGGL(k_stage1, dim3(AGG_BLKS + 105 + 176), dim3(256), 0, stream,
                       mid_agg_W, leaf, node, hist, gW, gb, mha_in_W, mha_in_b,
                       q_real, ent_W1, ent_b1, ent_W2, ent_b2,
                       mid_partial, out_causal, qkv, ent_scaled);

    hipLaunchKernelGGL(k_stage2, dim3(136), dim3(512), 0, stream,
                       qkv, o, ent_scaled, avg, mid_partial, mid_agg_b, mid_states,
                       mid_up_W1, mid_up_b1, mid_up_W2, mid_up_b2, cf);

    hipLaunchKernelGGL(k_stage3, dim3(142), dim3(512), 0, stream,
                       o, mha_out_W, mha_out_b, out_att,
                       q_real, q_imag, avg, meas_W, meas_b, out_meas,
                       root_agg_W, cf, root_part);

    hipLaunchKernelGGL(k_root, dim3(1), dim3(512), 0, stream,
                       root_part, root_agg_b, root_state,
                       root_up_W1, root_up_b1, root_up_W2, root_up_b2, out_root);
}